// Round 8
// baseline (157.099 us; speedup 1.0000x reference)
//
#include <hip/hip_runtime.h>
#include <math.h>

#define NB 256
#define NT 64
#define DIN 512
#define DSAE 4096
#define NK 32
#define HALF 2048

typedef float f32x4 __attribute__((ext_vector_type(4)));

// ---------------- xs[b,d] = sum_t x[b,t,d] + pesum[d]  (pesum recomputed per block) ----------------
__global__ __launch_bounds__(512) void k_xs(const float* __restrict__ x,
                                            float* __restrict__ xs,
                                            float* __restrict__ out) {
    const int b = blockIdx.x, d = threadIdx.x;   // grid NB, block 512
    if (b == 0 && d == 0) out[0] = 0.f;          // loss accumulator zero
    int j = d >> 1;
    float freq = expf((float)(2 * j) * (-9.210340371976184f / 512.0f));
    float pes = 0.f;
    if (d & 1) {
        for (int t = 0; t < NT; ++t) pes += cosf((float)t * freq);
    } else {
        for (int t = 0; t < NT; ++t) pes += sinf((float)t * freq);
    }
    const float* xp = x + (size_t)b * NT * DIN + d;
    float acc = 0.f;
#pragma unroll 16
    for (int t = 0; t < NT; ++t) acc += xp[(size_t)t * DIN];
    xs[(size_t)b * DIN + d] = acc + pes;
}

// ---------------- pre = xs @ W_enc + b_enc  (256x512 · 512x4096) ----------------
__global__ __launch_bounds__(256) void k_pre(const float* __restrict__ xs,
                                             const float* __restrict__ W,
                                             const float* __restrict__ b_enc,
                                             float* __restrict__ pre) {
    __shared__ float xs_t[DIN][8];   // transposed tile: [d][bb], 16 KB
    const int tid = threadIdx.x;
    const int s = blockIdx.x * 256 + tid;
    const int b0 = blockIdx.y * 8;
    for (int i = tid; i < 8 * DIN; i += 256) {
        int bb = i >> 9, d = i & 511;
        xs_t[d][bb] = xs[(size_t)(b0 + bb) * DIN + d];
    }
    __syncthreads();
    float a0=0,a1=0,a2=0,a3=0,a4=0,a5=0,a6=0,a7=0;
    float c0=0,c1=0,c2=0,c3=0,c4=0,c5=0,c6=0,c7=0;
    const float* wp = W + s;
#pragma unroll 4
    for (int d = 0; d < DIN; d += 2) {
        float w0 = wp[(size_t)d * DSAE];
        float w1 = wp[(size_t)(d + 1) * DSAE];
        float4 lo0 = *(const float4*)&xs_t[d][0];
        float4 hi0 = *(const float4*)&xs_t[d][4];
        float4 lo1 = *(const float4*)&xs_t[d + 1][0];
        float4 hi1 = *(const float4*)&xs_t[d + 1][4];
        a0 += lo0.x * w0; a1 += lo0.y * w0; a2 += lo0.z * w0; a3 += lo0.w * w0;
        a4 += hi0.x * w0; a5 += hi0.y * w0; a6 += hi0.z * w0; a7 += hi0.w * w0;
        c0 += lo1.x * w1; c1 += lo1.y * w1; c2 += lo1.z * w1; c3 += lo1.w * w1;
        c4 += hi1.x * w1; c5 += hi1.y * w1; c6 += hi1.z * w1; c7 += hi1.w * w1;
    }
    float be = b_enc[s];
    pre[(size_t)(b0 + 0) * DSAE + s] = a0 + c0 + be;
    pre[(size_t)(b0 + 1) * DSAE + s] = a1 + c1 + be;
    pre[(size_t)(b0 + 2) * DSAE + s] = a2 + c2 + be;
    pre[(size_t)(b0 + 3) * DSAE + s] = a3 + c3 + be;
    pre[(size_t)(b0 + 4) * DSAE + s] = a4 + c4 + be;
    pre[(size_t)(b0 + 5) * DSAE + s] = a5 + c5 + be;
    pre[(size_t)(b0 + 6) * DSAE + s] = a6 + c6 + be;
    pre[(size_t)(b0 + 7) * DSAE + s] = a7 + c7 + be;
}

// ---------------- top-32 per row: 1 wave/batch, hierarchical incremental argmax ----------------
__global__ __launch_bounds__(64) void k_topk(const float* __restrict__ pre,
                                             float* __restrict__ z_out,
                                             int* __restrict__ idx_s,
                                             float* __restrict__ zv_s) {
    const int b = blockIdx.x, lane = threadIdx.x;
    const float* pr = pre + (size_t)b * DSAE;
    float* zr = z_out + (size_t)b * DSAE;
    __shared__ float lv[64 * 65];
    __shared__ float lgv[64 * 8];
    __shared__ int   lga[64 * 8];
    for (int j = lane; j < DSAE; j += 64) __builtin_nontemporal_store(0.f, &zr[j]);
    const int base = lane * 65;
    float v[64];
#pragma unroll
    for (int j = 0; j < 64; ++j) v[j] = pr[j * 64 + lane];
#pragma unroll
    for (int j = 0; j < 64; ++j) lv[base + j] = v[j];
    float lmax = -INFINITY; int larg = 0;
#pragma unroll
    for (int g = 0; g < 8; ++g) {
        float m = v[g * 8]; int a = g * 8;
#pragma unroll
        for (int t = 1; t < 8; ++t)
            if (v[g * 8 + t] > m) { m = v[g * 8 + t]; a = g * 8 + t; }
        lgv[lane * 8 + g] = m; lga[lane * 8 + g] = a;
        if (m > lmax) { lmax = m; larg = a; }
    }
    __syncthreads();
    int myi = 0; float myv = 0.f;
    for (int k = 0; k < NK; ++k) {
        float bv = lmax; int be = larg * 64 + lane;
#pragma unroll
        for (int off = 32; off >= 1; off >>= 1) {
            float ov = __shfl_down(bv, off);
            int oe = __shfl_down(be, off);
            if (ov > bv || (ov == bv && oe < be)) { bv = ov; be = oe; }
        }
        bv = __shfl(bv, 0); be = __shfl(be, 0);
        if (lane == k) { myi = be; myv = bv > 0.f ? bv : 0.f; }
        if (lane == (be & 63)) {
            int j0 = be >> 6;
            lv[base + j0] = -INFINITY;
            int g0 = j0 >> 3;
            float m = -INFINITY; int a2 = g0 << 3;
            for (int t = 0; t < 8; ++t) {
                float x2 = lv[base + (g0 << 3) + t];
                if (x2 > m) { m = x2; a2 = (g0 << 3) + t; }
            }
            lgv[lane * 8 + g0] = m; lga[lane * 8 + g0] = a2;
            lmax = -INFINITY; larg = 0;
            for (int g = 0; g < 8; ++g) {
                float x2 = lgv[lane * 8 + g];
                if (x2 > lmax) { lmax = x2; larg = lga[lane * 8 + g]; }
            }
        }
    }
    int rank = 0;
#pragma unroll
    for (int j = 0; j < NK; ++j) {
        int oi = __shfl(myi, j);
        if (lane < NK && oi < myi) rank++;
    }
    if (lane < NK) {
        idx_s[b * NK + rank] = myi;
        zv_s[b * NK + rank] = myv;
        __builtin_nontemporal_store(myv, &zr[myi]);
    }
}

// ---------------- decoder, two passes over row ranges ----------------
// PASS 0: rows [0,2048): acc = b_dec + sum, nt-store partials to x_hat.
// PASS 1: rows [2048,4096): acc = readback(x_hat) + sum, fused loss, final store.
// Each pass's distinct gathered rows (~222 MB) fit the 256 MB L3 -> duplicates hit by
// construction. Accumulation order identical to single-pass (ascending rows); f32
// store/load round-trip of partials is exact.
template<int PASS>
__global__ __launch_bounds__(256) void k_dec(const float* __restrict__ x,
                                             const float* __restrict__ Wd,
                                             const float* __restrict__ bd,
                                             const int* __restrict__ idx_s,
                                             const float* __restrict__ zv_s,
                                             float* __restrict__ out) {
    const int b = blockIdx.y, chunk = blockIdx.x, tid = threadIdx.x;
    __shared__ int si[NK];
    __shared__ float sz[NK];
    if (tid < NK) { si[tid] = idx_s[b * NK + tid]; sz[tid] = zv_s[b * NK + tid]; }
    __syncthreads();
    const int f0 = chunk * 1024 + tid;            // float4 index within 32768-float row
    float* xh = out + 1 + (size_t)b * (NT * DIN); // 4B-aligned only

    float acc[16];
    if (PASS == 0) {
        const float4* bd4 = (const float4*)bd;
#pragma unroll
        for (int q = 0; q < 4; ++q) {
            float4 v = bd4[f0 + q * 256];
            acc[q*4+0] = v.x; acc[q*4+1] = v.y; acc[q*4+2] = v.z; acc[q*4+3] = v.w;
        }
    } else {
#pragma unroll
        for (int q = 0; q < 4; ++q) {
            int e = (f0 + q * 256) * 4;
            acc[q*4+0] = __builtin_nontemporal_load(&xh[e]);
            acc[q*4+1] = __builtin_nontemporal_load(&xh[e+1]);
            acc[q*4+2] = __builtin_nontemporal_load(&xh[e+2]);
            acc[q*4+3] = __builtin_nontemporal_load(&xh[e+3]);
        }
    }

    for (int k = 0; k < NK; ++k) {
        int s = si[k];
        if (PASS == 0) { if (s >= HALF) break; }       // sorted -> uniform break
        else           { if (s <  HALF) continue; }    // sorted -> uniform skip prefix
        const float4* w4 = (const float4*)(Wd + (size_t)s * (NT * DIN));
        float zk = sz[k];
        float4 w0 = w4[f0], w1 = w4[f0 + 256], w2 = w4[f0 + 512], w3 = w4[f0 + 768];
        acc[0]  += zk * w0.x; acc[1]  += zk * w0.y; acc[2]  += zk * w0.z; acc[3]  += zk * w0.w;
        acc[4]  += zk * w1.x; acc[5]  += zk * w1.y; acc[6]  += zk * w1.z; acc[7]  += zk * w1.w;
        acc[8]  += zk * w2.x; acc[9]  += zk * w2.y; acc[10] += zk * w2.z; acc[11] += zk * w2.w;
        acc[12] += zk * w3.x; acc[13] += zk * w3.y; acc[14] += zk * w3.z; acc[15] += zk * w3.w;
    }

    if (PASS == 0) {
        // store partials (nt, scalar: xh only 4B-aligned)
#pragma unroll
        for (int q = 0; q < 4; ++q) {
            int e = (f0 + q * 256) * 4;
            __builtin_nontemporal_store(acc[q*4+0], &xh[e]);
            __builtin_nontemporal_store(acc[q*4+1], &xh[e+1]);
            __builtin_nontemporal_store(acc[q*4+2], &xh[e+2]);
            __builtin_nontemporal_store(acc[q*4+3], &xh[e+3]);
        }
    } else {
        const f32x4* xr4 = (const f32x4*)(x + (size_t)b * (NT * DIN));
        float lsum = 0.f;
#pragma unroll
        for (int q = 0; q < 4; ++q) {
            f32x4 xv = __builtin_nontemporal_load(&xr4[f0 + q * 256]);
            float d0 = acc[q*4+0] - xv.x, d1 = acc[q*4+1] - xv.y;
            float d2 = acc[q*4+2] - xv.z, d3 = acc[q*4+3] - xv.w;
            lsum += d0 * d0; lsum += d1 * d1; lsum += d2 * d2; lsum += d3 * d3;
            int e = (f0 + q * 256) * 4;
            __builtin_nontemporal_store(acc[q*4+0], &xh[e]);
            __builtin_nontemporal_store(acc[q*4+1], &xh[e+1]);
            __builtin_nontemporal_store(acc[q*4+2], &xh[e+2]);
            __builtin_nontemporal_store(acc[q*4+3], &xh[e+3]);
        }
#pragma unroll
        for (int off = 32; off >= 1; off >>= 1) lsum += __shfl_down(lsum, off);
        __shared__ float red[4];
        if ((tid & 63) == 0) red[tid >> 6] = lsum;
        __syncthreads();
        if (tid == 0) {
            float tot = red[0] + red[1] + red[2] + red[3];
            atomicAdd(out, tot * (1.0f / (NB * NT)));
        }
    }
}

extern "C" void kernel_launch(void* const* d_in, const int* in_sizes, int n_in,
                              void* d_out, int out_size, void* d_ws, size_t ws_size,
                              hipStream_t stream) {
    const float* x     = (const float*)d_in[0];
    const float* W_enc = (const float*)d_in[1];
    const float* W_dec = (const float*)d_in[2];
    const float* b_enc = (const float*)d_in[3];
    const float* b_dec = (const float*)d_in[4];
    float* out = (float*)d_out;

    float* ws    = (float*)d_ws;
    float* xs    = ws;                        // 256*512   = 131072
    float* pre   = ws + 131072;               // 256*4096  = 1048576
    int*   idx_s = (int*)(ws + 1179648);      // 256*32 sorted indices
    float* zv_s  = ws + 1187840;              // 256*32 sorted values

    float* z_out = out + 1 + (size_t)NB * NT * DIN;  // z region

    k_xs<<<NB, 512, 0, stream>>>(x, xs, out);
    k_pre<<<dim3(16, 32), 256, 0, stream>>>(xs, W_enc, b_enc, pre);
    k_topk<<<NB, 64, 0, stream>>>(pre, z_out, idx_s, zv_s);
    k_dec<0><<<dim3(8, NB), 256, 0, stream>>>(x, W_dec, b_dec, idx_s, zv_s, out);
    k_dec<1><<<dim3(8, NB), 256, 0, stream>>>(x, W_dec, b_dec, idx_s, zv_s, out);
}

// Round 9
// 146.534 us; speedup vs baseline: 1.0721x; 1.0721x over previous
//
#include <hip/hip_runtime.h>
#include <math.h>

#define NB 256
#define NT 64
#define DIN 512
#define DSAE 4096
#define NK 32

typedef float f32x4 __attribute__((ext_vector_type(4)));

// ---------------- xs[b,d] = sum_t x[b,t,d] + pesum[d] ----------------
// 128 threads/block, one batch/block: thread owns float4 d4=tid; wave reads 1 KB/row.
__global__ __launch_bounds__(128) void k_xs(const float* __restrict__ x,
                                            float* __restrict__ xs,
                                            float* __restrict__ out) {
    const int b = blockIdx.x, t = threadIdx.x;   // grid NB, block 128
    if (b == 0 && t == 0) out[0] = 0.f;          // loss accumulator zero
    const float4* xr4 = (const float4*)(x + (size_t)b * NT * DIN);
    float4 acc = xr4[t];
#pragma unroll 9
    for (int r = 1; r < NT; ++r) {
        float4 v = xr4[r * 128 + t];
        acc.x += v.x; acc.y += v.y; acc.z += v.z; acc.w += v.w;
    }
    // pe column sums for d = 4t..4t+3 (same formula/order as scalar version)
    float freq_e = expf((float)(4 * t)     * (-9.210340371976184f / 512.0f));
    float freq_o = expf((float)(4 * t + 2) * (-9.210340371976184f / 512.0f));
    float s0 = 0.f, c0 = 0.f, s1 = 0.f, c1 = 0.f;
    for (int r = 0; r < NT; ++r) {
        float fr = (float)r;
        s0 += sinf(fr * freq_e); c0 += cosf(fr * freq_e);
        s1 += sinf(fr * freq_o); c1 += cosf(fr * freq_o);
    }
    acc.x += s0; acc.y += c0; acc.z += s1; acc.w += c1;
    ((float4*)(xs + (size_t)b * DIN))[t] = acc;
}

// ---------------- pre = xs @ W_enc + b_enc  (256x512 · 512x4096) ----------------
// grid (16 s-tiles, 16 b-tiles), block 512: half-groups (tid>>8) share W_enc columns
// -> W_enc delivered traffic halves. Per-thread inner loop identical to 8-batch version.
__global__ __launch_bounds__(512) void k_pre(const float* __restrict__ xs,
                                             const float* __restrict__ W,
                                             const float* __restrict__ b_enc,
                                             float* __restrict__ pre) {
    __shared__ float xs_t[DIN][16];   // transposed tile: [d][bb], 32 KB
    const int tid = threadIdx.x;
    const int s = blockIdx.x * 256 + (tid & 255);
    const int b0 = blockIdx.y * 16;
    const int bb0 = (tid >> 8) * 8;   // 0 or 8
    for (int i = tid; i < 16 * DIN; i += 512) {
        int bb = i >> 9, d = i & 511;
        xs_t[d][bb] = xs[(size_t)(b0 + bb) * DIN + d];
    }
    __syncthreads();
    // dual accumulators (even/odd d) for accuracy near the top-k rank boundary
    float a0=0,a1=0,a2=0,a3=0,a4=0,a5=0,a6=0,a7=0;
    float c0=0,c1=0,c2=0,c3=0,c4=0,c5=0,c6=0,c7=0;
    const float* wp = W + s;
#pragma unroll 4
    for (int d = 0; d < DIN; d += 2) {
        float w0 = wp[(size_t)d * DSAE];
        float w1 = wp[(size_t)(d + 1) * DSAE];
        float4 lo0 = *(const float4*)&xs_t[d][bb0];
        float4 hi0 = *(const float4*)&xs_t[d][bb0 + 4];
        float4 lo1 = *(const float4*)&xs_t[d + 1][bb0];
        float4 hi1 = *(const float4*)&xs_t[d + 1][bb0 + 4];
        a0 += lo0.x * w0; a1 += lo0.y * w0; a2 += lo0.z * w0; a3 += lo0.w * w0;
        a4 += hi0.x * w0; a5 += hi0.y * w0; a6 += hi0.z * w0; a7 += hi0.w * w0;
        c0 += lo1.x * w1; c1 += lo1.y * w1; c2 += lo1.z * w1; c3 += lo1.w * w1;
        c4 += hi1.x * w1; c5 += hi1.y * w1; c6 += hi1.z * w1; c7 += hi1.w * w1;
    }
    float be = b_enc[s];
    const int bo = b0 + bb0;
    pre[(size_t)(bo + 0) * DSAE + s] = a0 + c0 + be;
    pre[(size_t)(bo + 1) * DSAE + s] = a1 + c1 + be;
    pre[(size_t)(bo + 2) * DSAE + s] = a2 + c2 + be;
    pre[(size_t)(bo + 3) * DSAE + s] = a3 + c3 + be;
    pre[(size_t)(bo + 4) * DSAE + s] = a4 + c4 + be;
    pre[(size_t)(bo + 5) * DSAE + s] = a5 + c5 + be;
    pre[(size_t)(bo + 6) * DSAE + s] = a6 + c6 + be;
    pre[(size_t)(bo + 7) * DSAE + s] = a7 + c7 + be;
}

// ---------------- top-32 per row: 1 wave/batch, hierarchical incremental argmax ----------------
__global__ __launch_bounds__(64) void k_topk(const float* __restrict__ pre,
                                             float* __restrict__ z_out,
                                             int* __restrict__ idx_s,
                                             float* __restrict__ zv_s) {
    const int b = blockIdx.x, lane = threadIdx.x;
    const float* pr = pre + (size_t)b * DSAE;
    float* zr = z_out + (size_t)b * DSAE;
    __shared__ float lv[64 * 65];
    __shared__ float lgv[64 * 8];
    __shared__ int   lga[64 * 8];
    for (int j = lane; j < DSAE; j += 64) __builtin_nontemporal_store(0.f, &zr[j]);
    const int base = lane * 65;
    float v[64];
#pragma unroll
    for (int j = 0; j < 64; ++j) v[j] = pr[j * 64 + lane];
#pragma unroll
    for (int j = 0; j < 64; ++j) lv[base + j] = v[j];
    float lmax = -INFINITY; int larg = 0;
#pragma unroll
    for (int g = 0; g < 8; ++g) {
        float m = v[g * 8]; int a = g * 8;
#pragma unroll
        for (int t = 1; t < 8; ++t)
            if (v[g * 8 + t] > m) { m = v[g * 8 + t]; a = g * 8 + t; }
        lgv[lane * 8 + g] = m; lga[lane * 8 + g] = a;
        if (m > lmax) { lmax = m; larg = a; }
    }
    __syncthreads();
    int myi = 0; float myv = 0.f;
    for (int k = 0; k < NK; ++k) {
        float bv = lmax; int be = larg * 64 + lane;
#pragma unroll
        for (int off = 32; off >= 1; off >>= 1) {
            float ov = __shfl_down(bv, off);
            int oe = __shfl_down(be, off);
            if (ov > bv || (ov == bv && oe < be)) { bv = ov; be = oe; }
        }
        bv = __shfl(bv, 0); be = __shfl(be, 0);
        if (lane == k) { myi = be; myv = bv > 0.f ? bv : 0.f; }
        if (lane == (be & 63)) {
            int j0 = be >> 6;
            lv[base + j0] = -INFINITY;
            int g0 = j0 >> 3;
            float m = -INFINITY; int a2 = g0 << 3;
            for (int t = 0; t < 8; ++t) {
                float x2 = lv[base + (g0 << 3) + t];
                if (x2 > m) { m = x2; a2 = (g0 << 3) + t; }
            }
            lgv[lane * 8 + g0] = m; lga[lane * 8 + g0] = a2;
            lmax = -INFINITY; larg = 0;
            for (int g = 0; g < 8; ++g) {
                float x2 = lgv[lane * 8 + g];
                if (x2 > lmax) { lmax = x2; larg = lga[lane * 8 + g]; }
            }
        }
    }
    int rank = 0;
#pragma unroll
    for (int j = 0; j < NK; ++j) {
        int oi = __shfl(myi, j);
        if (lane < NK && oi < myi) rank++;
    }
    if (lane < NK) {
        idx_s[b * NK + rank] = myi;
        zv_s[b * NK + rank] = myv;
        __builtin_nontemporal_store(myv, &zr[myi]);
    }
}

// ---------------- decoder: x_hat = sum_k zv_k * W_dec[i_k] + b_dec ; fused loss ----------------
// R7-exact (at delivered-bytes limit: ~510 MB HBM + ~595 MB L3-hit delivery).
__global__ __launch_bounds__(256) void k_dec(const float* __restrict__ x,
                                             const float* __restrict__ Wd,
                                             const float* __restrict__ bd,
                                             const int* __restrict__ idx_s,
                                             const float* __restrict__ zv_s,
                                             float* __restrict__ out) {
    const int b = blockIdx.y, chunk = blockIdx.x, tid = threadIdx.x;
    __shared__ int si[NK];
    __shared__ float sz[NK];
    if (tid < NK) { si[tid] = idx_s[b * NK + tid]; sz[tid] = zv_s[b * NK + tid]; }
    __syncthreads();
    const int f0 = chunk * 1024 + tid;            // float4 index within 32768-float row
    const float4* bd4 = (const float4*)bd;
    float4 acc0 = bd4[f0];
    float4 acc1 = bd4[f0 + 256];
    float4 acc2 = bd4[f0 + 512];
    float4 acc3 = bd4[f0 + 768];
    for (int k = 0; k < NK; ++k) {
        const float4* w4 = (const float4*)(Wd + (size_t)si[k] * (NT * DIN));
        float zk = sz[k];
        float4 w0 = w4[f0], w1 = w4[f0 + 256], w2 = w4[f0 + 512], w3 = w4[f0 + 768];
        acc0.x += zk * w0.x; acc0.y += zk * w0.y; acc0.z += zk * w0.z; acc0.w += zk * w0.w;
        acc1.x += zk * w1.x; acc1.y += zk * w1.y; acc1.z += zk * w1.z; acc1.w += zk * w1.w;
        acc2.x += zk * w2.x; acc2.y += zk * w2.y; acc2.z += zk * w2.z; acc2.w += zk * w2.w;
        acc3.x += zk * w3.x; acc3.y += zk * w3.y; acc3.z += zk * w3.z; acc3.w += zk * w3.w;
    }
    const f32x4* xr4 = (const f32x4*)(x + (size_t)b * (NT * DIN));
    float* xh = out + 1 + (size_t)b * (NT * DIN);   // 4B-aligned only -> scalar stores
    float lsum = 0.f;
    {
        f32x4 xv = __builtin_nontemporal_load(&xr4[f0]);
        float d0 = acc0.x - xv.x, d1 = acc0.y - xv.y, d2 = acc0.z - xv.z, d3 = acc0.w - xv.w;
        lsum += d0 * d0; lsum += d1 * d1; lsum += d2 * d2; lsum += d3 * d3;
        int e = f0 * 4;
        __builtin_nontemporal_store(acc0.x, &xh[e]);   __builtin_nontemporal_store(acc0.y, &xh[e+1]);
        __builtin_nontemporal_store(acc0.z, &xh[e+2]); __builtin_nontemporal_store(acc0.w, &xh[e+3]);
    }
    {
        f32x4 xv = __builtin_nontemporal_load(&xr4[f0 + 256]);
        float d0 = acc1.x - xv.x, d1 = acc1.y - xv.y, d2 = acc1.z - xv.z, d3 = acc1.w - xv.w;
        lsum += d0 * d0; lsum += d1 * d1; lsum += d2 * d2; lsum += d3 * d3;
        int e = (f0 + 256) * 4;
        __builtin_nontemporal_store(acc1.x, &xh[e]);   __builtin_nontemporal_store(acc1.y, &xh[e+1]);
        __builtin_nontemporal_store(acc1.z, &xh[e+2]); __builtin_nontemporal_store(acc1.w, &xh[e+3]);
    }
    {
        f32x4 xv = __builtin_nontemporal_load(&xr4[f0 + 512]);
        float d0 = acc2.x - xv.x, d1 = acc2.y - xv.y, d2 = acc2.z - xv.z, d3 = acc2.w - xv.w;
        lsum += d0 * d0; lsum += d1 * d1; lsum += d2 * d2; lsum += d3 * d3;
        int e = (f0 + 512) * 4;
        __builtin_nontemporal_store(acc2.x, &xh[e]);   __builtin_nontemporal_store(acc2.y, &xh[e+1]);
        __builtin_nontemporal_store(acc2.z, &xh[e+2]); __builtin_nontemporal_store(acc2.w, &xh[e+3]);
    }
    {
        f32x4 xv = __builtin_nontemporal_load(&xr4[f0 + 768]);
        float d0 = acc3.x - xv.x, d1 = acc3.y - xv.y, d2 = acc3.z - xv.z, d3 = acc3.w - xv.w;
        lsum += d0 * d0; lsum += d1 * d1; lsum += d2 * d2; lsum += d3 * d3;
        int e = (f0 + 768) * 4;
        __builtin_nontemporal_store(acc3.x, &xh[e]);   __builtin_nontemporal_store(acc3.y, &xh[e+1]);
        __builtin_nontemporal_store(acc3.z, &xh[e+2]); __builtin_nontemporal_store(acc3.w, &xh[e+3]);
    }

#pragma unroll
    for (int off = 32; off >= 1; off >>= 1) lsum += __shfl_down(lsum, off);
    __shared__ float red[4];
    if ((tid & 63) == 0) red[tid >> 6] = lsum;
    __syncthreads();
    if (tid == 0) {
        float tot = red[0] + red[1] + red[2] + red[3];
        atomicAdd(out, tot * (1.0f / (NB * NT)));
    }
}

extern "C" void kernel_launch(void* const* d_in, const int* in_sizes, int n_in,
                              void* d_out, int out_size, void* d_ws, size_t ws_size,
                              hipStream_t stream) {
    const float* x     = (const float*)d_in[0];
    const float* W_enc = (const float*)d_in[1];
    const float* W_dec = (const float*)d_in[2];
    const float* b_enc = (const float*)d_in[3];
    const float* b_dec = (const float*)d_in[4];
    float* out = (float*)d_out;

    float* ws    = (float*)d_ws;
    float* xs    = ws;                        // 256*512   = 131072
    float* pre   = ws + 131072;               // 256*4096  = 1048576
    int*   idx_s = (int*)(ws + 1179648);      // 256*32 sorted indices
    float* zv_s  = ws + 1187840;              // 256*32 sorted values

    float* z_out = out + 1 + (size_t)NB * NT * DIN;  // z region

    k_xs<<<NB, 128, 0, stream>>>(x, xs, out);
    k_pre<<<dim3(16, 16), 512, 0, stream>>>(xs, W_enc, b_enc, pre);
    k_topk<<<NB, 64, 0, stream>>>(pre, z_out, idx_s, zv_s);
    k_dec<<<dim3(8, NB), 256, 0, stream>>>(x, W_dec, b_dec, idx_s, zv_s, out);
}

// Round 10
// 139.876 us; speedup vs baseline: 1.1231x; 1.0476x over previous
//
#include <hip/hip_runtime.h>
#include <math.h>

#define NB 256
#define NT 64
#define DIN 512
#define DSAE 4096
#define NK 32

typedef float f32x4 __attribute__((ext_vector_type(4)));

// ---------------- xs[b,d] = sum_t x[b,t,d] + pesum[d]  (pesum recomputed per block) ----------------
__global__ __launch_bounds__(512) void k_xs(const float* __restrict__ x,
                                            float* __restrict__ xs,
                                            float* __restrict__ out) {
    const int b = blockIdx.x, d = threadIdx.x;   // grid NB, block 512
    if (b == 0 && d == 0) out[0] = 0.f;          // loss accumulator zero (k_dec atomicAdds later)
    int j = d >> 1;
    float freq = expf((float)(2 * j) * (-9.210340371976184f / 512.0f));
    float pes = 0.f;
    if (d & 1) {
        for (int t = 0; t < NT; ++t) pes += cosf((float)t * freq);
    } else {
        for (int t = 0; t < NT; ++t) pes += sinf((float)t * freq);
    }
    const float* xp = x + (size_t)b * NT * DIN + d;
    float acc = 0.f;
#pragma unroll 16
    for (int t = 0; t < NT; ++t) acc += xp[(size_t)t * DIN];
    xs[(size_t)b * DIN + d] = acc + pes;
}

// ---------------- pre = xs @ W_enc + b_enc  (256x512 · 512x4096) ----------------
// grid (16 s-tiles, 32 b-tiles) = 512 blocks -> 2 blocks/CU -> 2 waves/SIMD (hide FMA latency).
__global__ __launch_bounds__(256) void k_pre(const float* __restrict__ xs,
                                             const float* __restrict__ W,
                                             const float* __restrict__ b_enc,
                                             float* __restrict__ pre) {
    __shared__ float xs_t[DIN][8];   // transposed tile: [d][bb], 16 KB
    const int tid = threadIdx.x;
    const int s = blockIdx.x * 256 + tid;
    const int b0 = blockIdx.y * 8;
    for (int i = tid; i < 8 * DIN; i += 256) {
        int bb = i >> 9, d = i & 511;
        xs_t[d][bb] = xs[(size_t)(b0 + bb) * DIN + d];
    }
    __syncthreads();
    // dual accumulators (even/odd d) for accuracy near the top-k rank boundary
    float a0=0,a1=0,a2=0,a3=0,a4=0,a5=0,a6=0,a7=0;
    float c0=0,c1=0,c2=0,c3=0,c4=0,c5=0,c6=0,c7=0;
    const float* wp = W + s;
#pragma unroll 4
    for (int d = 0; d < DIN; d += 2) {
        float w0 = wp[(size_t)d * DSAE];
        float w1 = wp[(size_t)(d + 1) * DSAE];
        float4 lo0 = *(const float4*)&xs_t[d][0];
        float4 hi0 = *(const float4*)&xs_t[d][4];
        float4 lo1 = *(const float4*)&xs_t[d + 1][0];
        float4 hi1 = *(const float4*)&xs_t[d + 1][4];
        a0 += lo0.x * w0; a1 += lo0.y * w0; a2 += lo0.z * w0; a3 += lo0.w * w0;
        a4 += hi0.x * w0; a5 += hi0.y * w0; a6 += hi0.z * w0; a7 += hi0.w * w0;
        c0 += lo1.x * w1; c1 += lo1.y * w1; c2 += lo1.z * w1; c3 += lo1.w * w1;
        c4 += hi1.x * w1; c5 += hi1.y * w1; c6 += hi1.z * w1; c7 += hi1.w * w1;
    }
    float be = b_enc[s];
    pre[(size_t)(b0 + 0) * DSAE + s] = a0 + c0 + be;
    pre[(size_t)(b0 + 1) * DSAE + s] = a1 + c1 + be;
    pre[(size_t)(b0 + 2) * DSAE + s] = a2 + c2 + be;
    pre[(size_t)(b0 + 3) * DSAE + s] = a3 + c3 + be;
    pre[(size_t)(b0 + 4) * DSAE + s] = a4 + c4 + be;
    pre[(size_t)(b0 + 5) * DSAE + s] = a5 + c5 + be;
    pre[(size_t)(b0 + 6) * DSAE + s] = a6 + c6 + be;
    pre[(size_t)(b0 + 7) * DSAE + s] = a7 + c7 + be;
}

// ---------------- top-32 per row: 1 wave/batch, hierarchical incremental argmax ----------------
__global__ __launch_bounds__(64) void k_topk(const float* __restrict__ pre,
                                             float* __restrict__ z_out,
                                             int* __restrict__ idx_s,
                                             float* __restrict__ zv_s) {
    const int b = blockIdx.x, lane = threadIdx.x;
    const float* pr = pre + (size_t)b * DSAE;
    float* zr = z_out + (size_t)b * DSAE;
    __shared__ float lv[64 * 65];
    __shared__ float lgv[64 * 8];
    __shared__ int   lga[64 * 8];
    for (int j = lane; j < DSAE; j += 64) __builtin_nontemporal_store(0.f, &zr[j]);
    const int base = lane * 65;
    float v[64];
#pragma unroll
    for (int j = 0; j < 64; ++j) v[j] = pr[j * 64 + lane];
#pragma unroll
    for (int j = 0; j < 64; ++j) lv[base + j] = v[j];
    float lmax = -INFINITY; int larg = 0;
#pragma unroll
    for (int g = 0; g < 8; ++g) {
        float m = v[g * 8]; int a = g * 8;
#pragma unroll
        for (int t = 1; t < 8; ++t)
            if (v[g * 8 + t] > m) { m = v[g * 8 + t]; a = g * 8 + t; }
        lgv[lane * 8 + g] = m; lga[lane * 8 + g] = a;
        if (m > lmax) { lmax = m; larg = a; }
    }
    __syncthreads();
    int myi = 0; float myv = 0.f;
    for (int k = 0; k < NK; ++k) {
        float bv = lmax; int be = larg * 64 + lane;
#pragma unroll
        for (int off = 32; off >= 1; off >>= 1) {
            float ov = __shfl_down(bv, off);
            int oe = __shfl_down(be, off);
            if (ov > bv || (ov == bv && oe < be)) { bv = ov; be = oe; }
        }
        bv = __shfl(bv, 0); be = __shfl(be, 0);
        if (lane == k) { myi = be; myv = bv > 0.f ? bv : 0.f; }
        if (lane == (be & 63)) {
            int j0 = be >> 6;
            lv[base + j0] = -INFINITY;
            int g0 = j0 >> 3;
            float m = -INFINITY; int a2 = g0 << 3;
            for (int t = 0; t < 8; ++t) {
                float x2 = lv[base + (g0 << 3) + t];
                if (x2 > m) { m = x2; a2 = (g0 << 3) + t; }
            }
            lgv[lane * 8 + g0] = m; lga[lane * 8 + g0] = a2;
            lmax = -INFINITY; larg = 0;
            for (int g = 0; g < 8; ++g) {
                float x2 = lgv[lane * 8 + g];
                if (x2 > lmax) { lmax = x2; larg = lga[lane * 8 + g]; }
            }
        }
    }
    int rank = 0;
#pragma unroll
    for (int j = 0; j < NK; ++j) {
        int oi = __shfl(myi, j);
        if (lane < NK && oi < myi) rank++;
    }
    if (lane < NK) {
        idx_s[b * NK + rank] = myi;
        zv_s[b * NK + rank] = myv;
        __builtin_nontemporal_store(myv, &zr[myi]);
    }
}

// ---------------- decoder: x_hat = sum_k zv_k * W_dec[i_k] + b_dec ; fused loss ----------------
// At delivered-bytes limit: ~443 MB distinct W_dec (HBM) + ~560 MB L3-hit delivery + x/x_hat.
__global__ __launch_bounds__(256) void k_dec(const float* __restrict__ x,
                                             const float* __restrict__ Wd,
                                             const float* __restrict__ bd,
                                             const int* __restrict__ idx_s,
                                             const float* __restrict__ zv_s,
                                             float* __restrict__ out) {
    const int b = blockIdx.y, chunk = blockIdx.x, tid = threadIdx.x;
    __shared__ int si[NK];
    __shared__ float sz[NK];
    if (tid < NK) { si[tid] = idx_s[b * NK + tid]; sz[tid] = zv_s[b * NK + tid]; }
    __syncthreads();
    const int f0 = chunk * 1024 + tid;            // float4 index within 32768-float row
    const float4* bd4 = (const float4*)bd;
    float4 acc0 = bd4[f0];
    float4 acc1 = bd4[f0 + 256];
    float4 acc2 = bd4[f0 + 512];
    float4 acc3 = bd4[f0 + 768];
    for (int k = 0; k < NK; ++k) {
        const float4* w4 = (const float4*)(Wd + (size_t)si[k] * (NT * DIN));
        float zk = sz[k];
        float4 w0 = w4[f0], w1 = w4[f0 + 256], w2 = w4[f0 + 512], w3 = w4[f0 + 768];
        acc0.x += zk * w0.x; acc0.y += zk * w0.y; acc0.z += zk * w0.z; acc0.w += zk * w0.w;
        acc1.x += zk * w1.x; acc1.y += zk * w1.y; acc1.z += zk * w1.z; acc1.w += zk * w1.w;
        acc2.x += zk * w2.x; acc2.y += zk * w2.y; acc2.z += zk * w2.z; acc2.w += zk * w2.w;
        acc3.x += zk * w3.x; acc3.y += zk * w3.y; acc3.z += zk * w3.z; acc3.w += zk * w3.w;
    }
    // x single-use -> nontemporal vector loads; loss per-quad (same add order as before)
    const f32x4* xr4 = (const f32x4*)(x + (size_t)b * (NT * DIN));
    float* xh = out + 1 + (size_t)b * (NT * DIN);   // 4B-aligned only -> scalar stores
    float lsum = 0.f;
    {
        f32x4 xv = __builtin_nontemporal_load(&xr4[f0]);
        float d0 = acc0.x - xv.x, d1 = acc0.y - xv.y, d2 = acc0.z - xv.z, d3 = acc0.w - xv.w;
        lsum += d0 * d0; lsum += d1 * d1; lsum += d2 * d2; lsum += d3 * d3;
        int e = f0 * 4;
        __builtin_nontemporal_store(acc0.x, &xh[e]);   __builtin_nontemporal_store(acc0.y, &xh[e+1]);
        __builtin_nontemporal_store(acc0.z, &xh[e+2]); __builtin_nontemporal_store(acc0.w, &xh[e+3]);
    }
    {
        f32x4 xv = __builtin_nontemporal_load(&xr4[f0 + 256]);
        float d0 = acc1.x - xv.x, d1 = acc1.y - xv.y, d2 = acc1.z - xv.z, d3 = acc1.w - xv.w;
        lsum += d0 * d0; lsum += d1 * d1; lsum += d2 * d2; lsum += d3 * d3;
        int e = (f0 + 256) * 4;
        __builtin_nontemporal_store(acc1.x, &xh[e]);   __builtin_nontemporal_store(acc1.y, &xh[e+1]);
        __builtin_nontemporal_store(acc1.z, &xh[e+2]); __builtin_nontemporal_store(acc1.w, &xh[e+3]);
    }
    {
        f32x4 xv = __builtin_nontemporal_load(&xr4[f0 + 512]);
        float d0 = acc2.x - xv.x, d1 = acc2.y - xv.y, d2 = acc2.z - xv.z, d3 = acc2.w - xv.w;
        lsum += d0 * d0; lsum += d1 * d1; lsum += d2 * d2; lsum += d3 * d3;
        int e = (f0 + 512) * 4;
        __builtin_nontemporal_store(acc2.x, &xh[e]);   __builtin_nontemporal_store(acc2.y, &xh[e+1]);
        __builtin_nontemporal_store(acc2.z, &xh[e+2]); __builtin_nontemporal_store(acc2.w, &xh[e+3]);
    }
    {
        f32x4 xv = __builtin_nontemporal_load(&xr4[f0 + 768]);
        float d0 = acc3.x - xv.x, d1 = acc3.y - xv.y, d2 = acc3.z - xv.z, d3 = acc3.w - xv.w;
        lsum += d0 * d0; lsum += d1 * d1; lsum += d2 * d2; lsum += d3 * d3;
        int e = (f0 + 768) * 4;
        __builtin_nontemporal_store(acc3.x, &xh[e]);   __builtin_nontemporal_store(acc3.y, &xh[e+1]);
        __builtin_nontemporal_store(acc3.z, &xh[e+2]); __builtin_nontemporal_store(acc3.w, &xh[e+3]);
    }

#pragma unroll
    for (int off = 32; off >= 1; off >>= 1) lsum += __shfl_down(lsum, off);
    __shared__ float red[4];
    if ((tid & 63) == 0) red[tid >> 6] = lsum;
    __syncthreads();
    if (tid == 0) {
        float tot = red[0] + red[1] + red[2] + red[3];
        atomicAdd(out, tot * (1.0f / (NB * NT)));
    }
}

extern "C" void kernel_launch(void* const* d_in, const int* in_sizes, int n_in,
                              void* d_out, int out_size, void* d_ws, size_t ws_size,
                              hipStream_t stream) {
    const float* x     = (const float*)d_in[0];
    const float* W_enc = (const float*)d_in[1];
    const float* W_dec = (const float*)d_in[2];
    const float* b_enc = (const float*)d_in[3];
    const float* b_dec = (const float*)d_in[4];
    float* out = (float*)d_out;

    float* ws    = (float*)d_ws;
    float* xs    = ws;                        // 256*512   = 131072
    float* pre   = ws + 131072;               // 256*4096  = 1048576
    int*   idx_s = (int*)(ws + 1179648);      // 256*32 sorted indices
    float* zv_s  = ws + 1187840;              // 256*32 sorted values

    float* z_out = out + 1 + (size_t)NB * NT * DIN;  // z region

    k_xs<<<NB, 512, 0, stream>>>(x, xs, out);
    k_pre<<<dim3(16, 32), 256, 0, stream>>>(xs, W_enc, b_enc, pre);
    k_topk<<<NB, 64, 0, stream>>>(pre, z_out, idx_s, zv_s);
    k_dec<<<dim3(8, NB), 256, 0, stream>>>(x, W_dec, b_dec, idx_s, zv_s, out);
}